// Round 17
// baseline (224.773 us; speedup 1.0000x reference)
//
#include <hip/hip_runtime.h>
#include <hip/hip_fp16.h>

#define D 128
#define TILE_R 64
#define NC 16     // histogram/cursor privatization copies
#define SFB 384   // scan_fill grid (must be co-resident: tiny kernel, 256 CUs)

typedef _Float16 h8 __attribute__((ext_vector_type(8)));
typedef float f4 __attribute__((ext_vector_type(4)));

// ---------------- prep: zero hist8 + sync + build MFMA fragment-ready W buffers ----------------
__global__ __launch_bounds__(256) void prep_kernel(int* __restrict__ hist8, int n8,
                                                   int* __restrict__ sync,
                                                   const float* __restrict__ W1,
                                                   __half* __restrict__ WB1,
                                                   const float* __restrict__ W2,
                                                   __half* __restrict__ WB2) {
    if (blockIdx.x < 2) {
        const float* W = blockIdx.x ? W2 : W1;
        __half* WB     = blockIdx.x ? WB2 : WB1;
        for (int idx = threadIdx.x; idx < D * D; idx += 256) {
            int j  = idx & 7;
            int l  = (idx >> 3) & 63;
            int kk = (idx >> 9) & 3;
            int c  = idx >> 11;
            int k   = kk * 32 + (l >> 4) * 8 + j;
            int col = c * 16 + (l & 15);
            WB[idx] = __float2half(W[col * D + k]);
        }
        return;
    }
    if (blockIdx.x == 2 && threadIdx.x < 8) sync[threadIdx.x] = 0;
    int i = (blockIdx.x - 2) * 256 + threadIdx.x;
    if (i < n8) hist8[i] = 0;
}

// ---------------- fragment loaders ----------------
__device__ inline h8 load_frag(const __half* p) { return *(const h8*)p; }
__device__ inline h8 load_frag(const float* p) {
    float4 u = *(const float4*)p;
    float4 v = *(const float4*)(p + 4);
    h8 r;
    r[0] = (_Float16)u.x; r[1] = (_Float16)u.y; r[2] = (_Float16)u.z; r[3] = (_Float16)u.w;
    r[4] = (_Float16)v.x; r[5] = (_Float16)v.y; r[6] = (_Float16)v.z; r[7] = (_Float16)v.w;
    return r;
}

// ---------------- MFMA linear with LDS-coalesced stores ----------------
template <typename T>
__device__ inline void linear_coal(const T* __restrict__ src,
                                   const __half* __restrict__ WB,
                                   __half* __restrict__ z, int n, int blk) {
    __shared__ __half Zs[64][132];
    int l    = threadIdx.x & 63;
    int wv   = threadIdx.x >> 6;
    int row0 = blk * TILE_R + wv * 16;
    int arow = row0 + (l & 15);
    bool rowok = arow < n;

    h8 a[4];
#pragma unroll
    for (int kk = 0; kk < 4; ++kk) {
        if (rowok)
            a[kk] = load_frag(&src[(size_t)arow * D + kk * 32 + (l >> 4) * 8]);
        else
            a[kk] = (h8)(_Float16)0.0f;
    }

    int lr0 = wv * 16 + (l >> 4) * 4;
#pragma unroll
    for (int c = 0; c < 8; ++c) {
        f4 acc = {0.f, 0.f, 0.f, 0.f};
#pragma unroll
        for (int kk = 0; kk < 4; ++kk) {
            h8 b = *(const h8*)&WB[(((c * 4 + kk) * 64) + l) * 8];
            acc = __builtin_amdgcn_mfma_f32_16x16x32_f16(a[kk], b, acc, 0, 0, 0);
        }
        int col = c * 16 + (l & 15);
#pragma unroll
        for (int r = 0; r < 4; ++r) Zs[lr0 + r][col] = __float2half(acc[r]);
    }
    __syncthreads();

    int row = threadIdx.x >> 2;
    int cb  = (threadIdx.x & 3) * 32;
    int gro = blk * TILE_R + row;
    if (gro < n) {
        float2 p0 = *(const float2*)&Zs[row][cb];
        float2 p1 = *(const float2*)&Zs[row][cb + 4];
        float2 p2 = *(const float2*)&Zs[row][cb + 8];
        float2 p3 = *(const float2*)&Zs[row][cb + 12];
        float2 p4 = *(const float2*)&Zs[row][cb + 16];
        float2 p5 = *(const float2*)&Zs[row][cb + 20];
        float2 p6 = *(const float2*)&Zs[row][cb + 24];
        float2 p7 = *(const float2*)&Zs[row][cb + 28];
        __half* zp = &z[(size_t)gro * D + cb];
        *(float4*)(zp)      = make_float4(p0.x, p0.y, p1.x, p1.y);
        *(float4*)(zp + 8)  = make_float4(p2.x, p2.y, p3.x, p3.y);
        *(float4*)(zp + 16) = make_float4(p4.x, p4.y, p5.x, p5.y);
        *(float4*)(zp + 24) = make_float4(p6.x, p6.y, p7.x, p7.y);
    }
}

// ---------------- fused: round-1 linear (blocks 0..nlin-1) + histogram (rest) ----------------
// hist copy chosen by EDGE CHUNK index ((i>>8)&(NC-1)) so fill can reproduce it.
__global__ __launch_bounds__(256) void hist_linear_kernel(const int* __restrict__ ei, int e,
                                                          int* __restrict__ hist8, int nlin,
                                                          const float* __restrict__ x,
                                                          const __half* __restrict__ WB,
                                                          __half* __restrict__ z, int n) {
    if (blockIdx.x >= nlin) {
        int chunk = blockIdx.x - nlin;
        int i = chunk * 256 + threadIdx.x;
        if (i < e) atomicAdd(&hist8[(chunk & (NC - 1)) * n + ei[i]], 1);
        return;
    }
    linear_coal<float>(x, WB, z, n, blockIdx.x);
}

// ---------------- in-kernel grid barrier (all SFB blocks co-resident) ----------------
__device__ inline void gsync(int* cnt, int target) {
    __syncthreads();
    if (threadIdx.x == 0) {
        __threadfence();
        atomicAdd(cnt, 1);
        while (atomicAdd(cnt, 0) < target) {}
        __threadfence();
    }
    __syncthreads();
}

// ---------------- merged: partial sums -> barrier -> finalize -> barrier -> CSR fill ----------------
__global__ __launch_bounds__(256) void scan_fill_kernel(const int* __restrict__ ei, int e,
                                                        int* __restrict__ hist8,
                                                        int* __restrict__ bsum,
                                                        int* __restrict__ sync,
                                                        int* __restrict__ offsets,
                                                        int* __restrict__ deg,
                                                        int* __restrict__ cursor8,
                                                        float* __restrict__ rdeg,
                                                        int* __restrict__ csr,
                                                        int n, int nscanb) {
    __shared__ int wt[4];
    int t = threadIdx.x, lane = t & 63, w = t >> 6;

    // ---- phase A: per-block partial sums of node totals ----
    if (blockIdx.x < nscanb) {
        int i = blockIdx.x * 256 + t;
        int v = 0;
        if (i < n) {
#pragma unroll
            for (int c = 0; c < NC; ++c) v += hist8[c * n + i];
        }
#pragma unroll
        for (int off = 1; off < 64; off <<= 1) v += __shfl_xor(v, off);
        if (lane == 0) wt[w] = v;
        __syncthreads();
        if (t == 0) bsum[blockIdx.x] = wt[0] + wt[1] + wt[2] + wt[3];
    }
    gsync(&sync[0], gridDim.x);

    // ---- phase B: finalize offsets/deg/rdeg + per-copy sub-segment cursors ----
    if (blockIdx.x < nscanb) {
        int p = 0;
        for (int k = t; k < blockIdx.x; k += 256) p += bsum[k];
#pragma unroll
        for (int off = 1; off < 64; off <<= 1) p += __shfl_xor(p, off);
        __syncthreads();   // wt reuse
        if (lane == 0) wt[w] = p;
        __syncthreads();
        int blockbase = wt[0] + wt[1] + wt[2] + wt[3];

        int i = blockIdx.x * 256 + t;
        int cnt[NC];
        int tot = 0;
        if (i < n) {
#pragma unroll
            for (int c = 0; c < NC; ++c) { cnt[c] = hist8[c * n + i]; tot += cnt[c]; }
        } else {
#pragma unroll
            for (int c = 0; c < NC; ++c) cnt[c] = 0;
        }
        int iv = tot;
#pragma unroll
        for (int off = 1; off < 64; off <<= 1) {
            int n2 = __shfl_up(iv, off);
            if (lane >= off) iv += n2;
        }
        __syncthreads();
        if (lane == 63) wt[w] = iv;
        __syncthreads();
        int add = blockbase;
        for (int k = 0; k < w; ++k) add += wt[k];
        int excl = iv - tot + add;
        if (i < n) {
            offsets[i] = excl;
            deg[i]     = tot;
            rdeg[i]    = 1.0f / fmaxf((float)tot, 1.0f);
            int run = excl;
#pragma unroll
            for (int c = 0; c < NC; ++c) { cursor8[c * n + i] = run; run += cnt[c]; }
        }
    }
    gsync(&sync[1], gridDim.x);

    // ---- phase C: grid-stride CSR fill (copy = edge-chunk & (NC-1), block-independent) ----
    for (int i = blockIdx.x * 256 + t; i < e; i += gridDim.x * 256) {
        int r = ei[i];
        int c = ei[e + i];
        int pos = atomicAdd(&cursor8[((i >> 8) & (NC - 1)) * n + r], 1);
        csr[pos] = c;
    }
}

// ---------------- gather core: accumulate node's neighbor rows of z (fp16) ----------------
__device__ inline void addh8(float* a, float4 v) {
    const __half2* h = (const __half2*)&v;
    float2 f0 = __half22float2(h[0]);
    float2 f1 = __half22float2(h[1]);
    float2 f2 = __half22float2(h[2]);
    float2 f3 = __half22float2(h[3]);
    a[0] += f0.x; a[1] += f0.y; a[2] += f1.x; a[3] += f1.y;
    a[4] += f2.x; a[5] += f2.y; a[6] += f3.x; a[7] += f3.y;
}

__device__ inline void gather_core(const float4* __restrict__ base, int start, int cnt,
                                   int gl, const int* __restrict__ csr, float* acc) {
    int i = 0;
    for (; i + 8 <= cnt; i += 8) {
        int c0 = csr[start + i];
        int c1 = csr[start + i + 1];
        int c2 = csr[start + i + 2];
        int c3 = csr[start + i + 3];
        int c4 = csr[start + i + 4];
        int c5 = csr[start + i + 5];
        int c6 = csr[start + i + 6];
        int c7 = csr[start + i + 7];
        float4 v0 = base[(size_t)c0 * 16 + gl];
        float4 v1 = base[(size_t)c1 * 16 + gl];
        float4 v2 = base[(size_t)c2 * 16 + gl];
        float4 v3 = base[(size_t)c3 * 16 + gl];
        float4 v4 = base[(size_t)c4 * 16 + gl];
        float4 v5 = base[(size_t)c5 * 16 + gl];
        float4 v6 = base[(size_t)c6 * 16 + gl];
        float4 v7 = base[(size_t)c7 * 16 + gl];
        addh8(acc, v0); addh8(acc, v1); addh8(acc, v2); addh8(acc, v3);
        addh8(acc, v4); addh8(acc, v5); addh8(acc, v6); addh8(acc, v7);
    }
    if (i + 4 <= cnt) {
        int c0 = csr[start + i];
        int c1 = csr[start + i + 1];
        int c2 = csr[start + i + 2];
        int c3 = csr[start + i + 3];
        float4 v0 = base[(size_t)c0 * 16 + gl];
        float4 v1 = base[(size_t)c1 * 16 + gl];
        float4 v2 = base[(size_t)c2 * 16 + gl];
        float4 v3 = base[(size_t)c3 * 16 + gl];
        addh8(acc, v0); addh8(acc, v1); addh8(acc, v2); addh8(acc, v3);
        i += 4;
    }
    int rem = cnt - i;
    if (rem > 0) {
        int c0 = csr[start + i];
        int c1 = csr[start + min(i + 1, cnt - 1)];
        int c2 = csr[start + min(i + 2, cnt - 1)];
        float4 v0 = base[(size_t)c0 * 16 + gl];
        float4 v1 = base[(size_t)c1 * 16 + gl];
        float4 v2 = base[(size_t)c2 * 16 + gl];
        addh8(acc, v0);
        if (rem > 1) addh8(acc, v1);
        if (rem > 2) addh8(acc, v2);
    }
}

// ---------------- fused: gather round-1 into LDS tile, then linear2 -> z2 ----------------
__global__ __launch_bounds__(512) void gather_linear_kernel(const __half* __restrict__ z1,
                                                            const int* __restrict__ offsets,
                                                            const int* __restrict__ deg,
                                                            const int* __restrict__ csr,
                                                            const float* __restrict__ rdeg,
                                                            const float* __restrict__ bias,
                                                            const __half* __restrict__ WB2,
                                                            __half* __restrict__ z2, int n) {
    __shared__ __half Hs[32][136];
    int t    = threadIdx.x;
    int wv   = t >> 6;
    int lane = t & 63;
    int g    = lane >> 4;
    int gl   = lane & 15;
    int lrow = wv * 4 + g;
    int node = blockIdx.x * 32 + lrow;

    if (node < n) {
        float acc[8] = {0.f, 0.f, 0.f, 0.f, 0.f, 0.f, 0.f, 0.f};
        gather_core((const float4*)z1, offsets[node], deg[node], gl, csr, acc);
        float rd = rdeg[node];
        float4 b0 = ((const float4*)bias)[gl * 2];
        float4 b1 = ((const float4*)bias)[gl * 2 + 1];
        __half2 hp[4];
        hp[0] = __float22half2_rn(make_float2(fmaxf(acc[0] * rd + b0.x, 0.f),
                                              fmaxf(acc[1] * rd + b0.y, 0.f)));
        hp[1] = __float22half2_rn(make_float2(fmaxf(acc[2] * rd + b0.z, 0.f),
                                              fmaxf(acc[3] * rd + b0.w, 0.f)));
        hp[2] = __float22half2_rn(make_float2(fmaxf(acc[4] * rd + b1.x, 0.f),
                                              fmaxf(acc[5] * rd + b1.y, 0.f)));
        hp[3] = __float22half2_rn(make_float2(fmaxf(acc[6] * rd + b1.z, 0.f),
                                              fmaxf(acc[7] * rd + b1.w, 0.f)));
        *(float4*)&Hs[lrow][gl * 8] = *(const float4*)hp;
    }
    __syncthreads();

    int r0 = (wv >> 2) * 16;
    int arow = r0 + (lane & 15);
    h8 a[4];
#pragma unroll
    for (int kk = 0; kk < 4; ++kk)
        a[kk] = *(const h8*)&Hs[arow][kk * 32 + (lane >> 4) * 8];

    int srow = blockIdx.x * 32 + r0 + (lane >> 4) * 4;
#pragma unroll
    for (int cc = 0; cc < 2; ++cc) {
        int c = (wv & 3) * 2 + cc;
        f4 acc = {0.f, 0.f, 0.f, 0.f};
#pragma unroll
        for (int kk = 0; kk < 4; ++kk) {
            h8 b = *(const h8*)&WB2[(((c * 4 + kk) * 64) + lane) * 8];
            acc = __builtin_amdgcn_mfma_f32_16x16x32_f16(a[kk], b, acc, 0, 0, 0);
        }
        int col = c * 16 + (lane & 15);
#pragma unroll
        for (int r = 0; r < 4; ++r) {
            int ro = srow + r;
            if (ro < n) z2[(size_t)ro * D + col] = __float2half(acc[r]);
        }
    }
}

// ---------------- final gather: z2 -> out (f32) ----------------
__global__ __launch_bounds__(256) void gather_kernel(const __half* __restrict__ z,
                                                     const int* __restrict__ offsets,
                                                     const int* __restrict__ deg,
                                                     const int* __restrict__ csr,
                                                     const float* __restrict__ rdeg,
                                                     const float* __restrict__ bias,
                                                     float* __restrict__ out, int n) {
    int tid  = blockIdx.x * 256 + threadIdx.x;
    int wave = tid >> 6;
    int lane = threadIdx.x & 63;
    int g    = lane >> 4;
    int gl   = lane & 15;
    int node = wave * 4 + g;
    if (node >= n) return;

    float acc[8] = {0.f, 0.f, 0.f, 0.f, 0.f, 0.f, 0.f, 0.f};
    gather_core((const float4*)z, offsets[node], deg[node], gl, csr, acc);

    float rd = rdeg[node];
    float4 b0 = ((const float4*)bias)[gl * 2];
    float4 b1 = ((const float4*)bias)[gl * 2 + 1];
    float4* o4 = (float4*)out;
    o4[(size_t)node * 32 + gl * 2] =
        make_float4(fmaxf(acc[0] * rd + b0.x, 0.f), fmaxf(acc[1] * rd + b0.y, 0.f),
                    fmaxf(acc[2] * rd + b0.z, 0.f), fmaxf(acc[3] * rd + b0.w, 0.f));
    o4[(size_t)node * 32 + gl * 2 + 1] =
        make_float4(fmaxf(acc[4] * rd + b1.x, 0.f), fmaxf(acc[5] * rd + b1.y, 0.f),
                    fmaxf(acc[6] * rd + b1.z, 0.f), fmaxf(acc[7] * rd + b1.w, 0.f));
}

extern "C" void kernel_launch(void* const* d_in, const int* in_sizes, int n_in,
                              void* d_out, int out_size, void* d_ws, size_t ws_size,
                              hipStream_t stream) {
    const float* x  = (const float*)d_in[0];
    const int*   ei = (const int*)d_in[1];
    const float* W1 = (const float*)d_in[2];
    const float* b1 = (const float*)d_in[3];
    const float* W2 = (const float*)d_in[4];
    const float* b2 = (const float*)d_in[5];
    float* out = (float*)d_out;

    int N = in_sizes[0] / D;   // 50000
    int E = in_sizes[1] / 2;   // 600000
    int NB = (N + 255) / 256;  // 196 scan blocks

    // workspace carve (16B-aligned: N, E multiples of 4)
    int* hist8   = (int*)d_ws;               // [NC][N]
    int* cursor8 = hist8 + NC * N;           // [NC][N]
    int* offsets = cursor8 + NC * N;
    int* deg     = offsets + N;
    int* csr     = deg + N;
    float* rdeg  = (float*)(csr + E);
    int* bsum    = (int*)(rdeg + N);
    int* sync    = bsum + ((NB + 3) & ~3);
    __half* WB1  = (__half*)(sync + 8);
    __half* WB2  = WB1 + D * D;
    __half* zz   = WB2 + D * D;              // z1, fp16 [N][D]
    __half* zz2  = zz + (size_t)N * D;       // z2, fp16 [N][D]

    int NZ    = (NC * N + 255) / 256;              // hist8 zero blocks
    int nhist = (E + 255) / 256;                   // 2344
    int nblk  = (N + TILE_R - 1) / TILE_R;         // 782 (round-1 linear)
    int gfblk = (N + 31) / 32;                     // 1563 (fused gather+linear2)
    int gblk  = ((N + 3) / 4 * 64 + 255) / 256;    // final gather blocks

    prep_kernel<<<NZ + 2, 256, 0, stream>>>(hist8, NC * N, sync, W1, WB1, W2, WB2);
    // fused: z1 = x @ W1^T (blocks 0..nblk-1) + privatized histogram (rest)
    hist_linear_kernel<<<nblk + nhist, 256, 0, stream>>>(ei, E, hist8, nblk, x, WB1, zz, N);
    // merged scan+fill: partials -> gbar -> finalize -> gbar -> CSR fill
    scan_fill_kernel<<<SFB, 256, 0, stream>>>(ei, E, hist8, bsum, sync, offsets, deg,
                                              cursor8, rdeg, csr, N, NB);
    // fused: h = relu(S z1 + b1) ; z2 = h @ W2^T
    gather_linear_kernel<<<gfblk, 512, 0, stream>>>(zz, offsets, deg, csr, rdeg, b1,
                                                    WB2, zz2, N);
    // final: out = relu(S z2 + b2)
    gather_kernel<<<gblk, 256, 0, stream>>>(zz2, offsets, deg, csr, rdeg, b2, out, N);
}

// Round 18
// 150.717 us; speedup vs baseline: 1.4914x; 1.4914x over previous
//
#include <hip/hip_runtime.h>
#include <hip/hip_fp16.h>

#define D 128
#define TILE_R 64
#define NC 16   // histogram/cursor privatization copies

typedef _Float16 h8 __attribute__((ext_vector_type(8)));
typedef float f4 __attribute__((ext_vector_type(4)));

// ---------------- prep: zero hist8 + build MFMA fragment-ready W buffers ----------------
__global__ __launch_bounds__(256) void prep_kernel(int* __restrict__ hist8, int n8,
                                                   const float* __restrict__ W1,
                                                   __half* __restrict__ WB1,
                                                   const float* __restrict__ W2,
                                                   __half* __restrict__ WB2) {
    if (blockIdx.x < 2) {
        const float* W = blockIdx.x ? W2 : W1;
        __half* WB     = blockIdx.x ? WB2 : WB1;
        for (int idx = threadIdx.x; idx < D * D; idx += 256) {
            int j  = idx & 7;
            int l  = (idx >> 3) & 63;
            int kk = (idx >> 9) & 3;
            int c  = idx >> 11;
            int k   = kk * 32 + (l >> 4) * 8 + j;
            int col = c * 16 + (l & 15);
            WB[idx] = __float2half(W[col * D + k]);
        }
        return;
    }
    int i = (blockIdx.x - 2) * 256 + threadIdx.x;
    if (i < n8) hist8[i] = 0;
}

// ---------------- fragment loaders ----------------
__device__ inline h8 load_frag(const __half* p) { return *(const h8*)p; }
__device__ inline h8 load_frag(const float* p) {
    float4 u = *(const float4*)p;
    float4 v = *(const float4*)(p + 4);
    h8 r;
    r[0] = (_Float16)u.x; r[1] = (_Float16)u.y; r[2] = (_Float16)u.z; r[3] = (_Float16)u.w;
    r[4] = (_Float16)v.x; r[5] = (_Float16)v.y; r[6] = (_Float16)v.z; r[7] = (_Float16)v.w;
    return r;
}

// ---------------- MFMA linear with LDS-coalesced stores ----------------
template <typename T>
__device__ inline void linear_coal(const T* __restrict__ src,
                                   const __half* __restrict__ WB,
                                   __half* __restrict__ z, int n, int blk) {
    __shared__ __half Zs[64][132];
    int l    = threadIdx.x & 63;
    int wv   = threadIdx.x >> 6;
    int row0 = blk * TILE_R + wv * 16;
    int arow = row0 + (l & 15);
    bool rowok = arow < n;

    h8 a[4];
#pragma unroll
    for (int kk = 0; kk < 4; ++kk) {
        if (rowok)
            a[kk] = load_frag(&src[(size_t)arow * D + kk * 32 + (l >> 4) * 8]);
        else
            a[kk] = (h8)(_Float16)0.0f;
    }

    int lr0 = wv * 16 + (l >> 4) * 4;
#pragma unroll
    for (int c = 0; c < 8; ++c) {
        f4 acc = {0.f, 0.f, 0.f, 0.f};
#pragma unroll
        for (int kk = 0; kk < 4; ++kk) {
            h8 b = *(const h8*)&WB[(((c * 4 + kk) * 64) + l) * 8];
            acc = __builtin_amdgcn_mfma_f32_16x16x32_f16(a[kk], b, acc, 0, 0, 0);
        }
        int col = c * 16 + (l & 15);
#pragma unroll
        for (int r = 0; r < 4; ++r) Zs[lr0 + r][col] = __float2half(acc[r]);
    }
    __syncthreads();

    int row = threadIdx.x >> 2;
    int cb  = (threadIdx.x & 3) * 32;
    int gro = blk * TILE_R + row;
    if (gro < n) {
        float2 p0 = *(const float2*)&Zs[row][cb];
        float2 p1 = *(const float2*)&Zs[row][cb + 4];
        float2 p2 = *(const float2*)&Zs[row][cb + 8];
        float2 p3 = *(const float2*)&Zs[row][cb + 12];
        float2 p4 = *(const float2*)&Zs[row][cb + 16];
        float2 p5 = *(const float2*)&Zs[row][cb + 20];
        float2 p6 = *(const float2*)&Zs[row][cb + 24];
        float2 p7 = *(const float2*)&Zs[row][cb + 28];
        __half* zp = &z[(size_t)gro * D + cb];
        *(float4*)(zp)      = make_float4(p0.x, p0.y, p1.x, p1.y);
        *(float4*)(zp + 8)  = make_float4(p2.x, p2.y, p3.x, p3.y);
        *(float4*)(zp + 16) = make_float4(p4.x, p4.y, p5.x, p5.y);
        *(float4*)(zp + 24) = make_float4(p6.x, p6.y, p7.x, p7.y);
    }
}

// ---------------- fused: round-1 linear (blocks 0..nlin-1) + histogram (rest) ----------------
// hist copy chosen by EDGE CHUNK index so fill can reproduce it.
__global__ __launch_bounds__(256) void hist_linear_kernel(const int* __restrict__ ei, int e,
                                                          int* __restrict__ hist8, int nlin,
                                                          const float* __restrict__ x,
                                                          const __half* __restrict__ WB,
                                                          __half* __restrict__ z, int n) {
    if (blockIdx.x >= nlin) {
        int chunk = blockIdx.x - nlin;
        int i = chunk * 256 + threadIdx.x;
        if (i < e) atomicAdd(&hist8[(chunk & (NC - 1)) * n + ei[i]], 1);
        return;
    }
    linear_coal<float>(x, WB, z, n, blockIdx.x);
}

// ---------------- per-block partial sums over node totals ----------------
__global__ __launch_bounds__(256) void partial_kernel(const int* __restrict__ hist8,
                                                      int* __restrict__ bsum, int n) {
    int i = blockIdx.x * 256 + threadIdx.x;
    int v = 0;
    if (i < n) {
#pragma unroll
        for (int c = 0; c < NC; ++c) v += hist8[c * n + i];
    }
#pragma unroll
    for (int off = 1; off < 64; off <<= 1) v += __shfl_xor(v, off);
    __shared__ int ws[4];
    int lane = threadIdx.x & 63, w = threadIdx.x >> 6;
    if (lane == 0) ws[w] = v;
    __syncthreads();
    if (threadIdx.x == 0) bsum[blockIdx.x] = ws[0] + ws[1] + ws[2] + ws[3];
}

// ---------------- finalize: offsets/deg/rdeg + per-copy sub-segment cursors ----------------
__global__ __launch_bounds__(256) void finalize_kernel(const int* __restrict__ hist8,
                                                       const int* __restrict__ bsum,
                                                       int* __restrict__ offsets,
                                                       int* __restrict__ deg,
                                                       int* __restrict__ cursor8,
                                                       float* __restrict__ rdeg, int n) {
    __shared__ int wt[4];
    int t = threadIdx.x, lane = t & 63, w = t >> 6;

    int p = 0;
    for (int k = t; k < blockIdx.x; k += 256) p += bsum[k];
#pragma unroll
    for (int off = 1; off < 64; off <<= 1) p += __shfl_xor(p, off);
    if (lane == 0) wt[w] = p;
    __syncthreads();
    int blockbase = wt[0] + wt[1] + wt[2] + wt[3];
    __syncthreads();

    int i = blockIdx.x * 256 + t;
    int cnt[NC];
    int tot = 0;
    if (i < n) {
#pragma unroll
        for (int c = 0; c < NC; ++c) { cnt[c] = hist8[c * n + i]; tot += cnt[c]; }
    } else {
#pragma unroll
        for (int c = 0; c < NC; ++c) cnt[c] = 0;
    }
    int iv = tot;
#pragma unroll
    for (int off = 1; off < 64; off <<= 1) {
        int n2 = __shfl_up(iv, off);
        if (lane >= off) iv += n2;
    }
    if (lane == 63) wt[w] = iv;
    __syncthreads();
    int add = blockbase;
    for (int k = 0; k < w; ++k) add += wt[k];
    int excl = iv - tot + add;
    if (i < n) {
        offsets[i] = excl;
        deg[i]     = tot;
        rdeg[i]    = 1.0f / fmaxf((float)tot, 1.0f);
        int run = excl;
#pragma unroll
        for (int c = 0; c < NC; ++c) { cursor8[c * n + i] = run; run += cnt[c]; }
    }
}

// ---------------- fill CSR via privatized cursors (copy = edge chunk & (NC-1)) ----------------
__global__ __launch_bounds__(256) void fill_kernel(const int* __restrict__ ei, int e,
                                                   int* __restrict__ cursor8,
                                                   int* __restrict__ csr, int n) {
    int i = blockIdx.x * 256 + threadIdx.x;
    if (i < e) {
        int r = ei[i];
        int c = ei[e + i];
        int pos = atomicAdd(&cursor8[(blockIdx.x & (NC - 1)) * n + r], 1);
        csr[pos] = c;
    }
}

// ---------------- gather core: accumulate node's neighbor rows of z (fp16) ----------------
__device__ inline void addh8(float* a, float4 v) {
    const __half2* h = (const __half2*)&v;
    float2 f0 = __half22float2(h[0]);
    float2 f1 = __half22float2(h[1]);
    float2 f2 = __half22float2(h[2]);
    float2 f3 = __half22float2(h[3]);
    a[0] += f0.x; a[1] += f0.y; a[2] += f1.x; a[3] += f1.y;
    a[4] += f2.x; a[5] += f2.y; a[6] += f3.x; a[7] += f3.y;
}

__device__ inline void gather_core(const float4* __restrict__ base, int start, int cnt,
                                   int gl, const int* __restrict__ csr, float* acc) {
    int i = 0;
    for (; i + 8 <= cnt; i += 8) {
        int c0 = csr[start + i];
        int c1 = csr[start + i + 1];
        int c2 = csr[start + i + 2];
        int c3 = csr[start + i + 3];
        int c4 = csr[start + i + 4];
        int c5 = csr[start + i + 5];
        int c6 = csr[start + i + 6];
        int c7 = csr[start + i + 7];
        float4 v0 = base[(size_t)c0 * 16 + gl];
        float4 v1 = base[(size_t)c1 * 16 + gl];
        float4 v2 = base[(size_t)c2 * 16 + gl];
        float4 v3 = base[(size_t)c3 * 16 + gl];
        float4 v4 = base[(size_t)c4 * 16 + gl];
        float4 v5 = base[(size_t)c5 * 16 + gl];
        float4 v6 = base[(size_t)c6 * 16 + gl];
        float4 v7 = base[(size_t)c7 * 16 + gl];
        addh8(acc, v0); addh8(acc, v1); addh8(acc, v2); addh8(acc, v3);
        addh8(acc, v4); addh8(acc, v5); addh8(acc, v6); addh8(acc, v7);
    }
    if (i + 4 <= cnt) {
        int c0 = csr[start + i];
        int c1 = csr[start + i + 1];
        int c2 = csr[start + i + 2];
        int c3 = csr[start + i + 3];
        float4 v0 = base[(size_t)c0 * 16 + gl];
        float4 v1 = base[(size_t)c1 * 16 + gl];
        float4 v2 = base[(size_t)c2 * 16 + gl];
        float4 v3 = base[(size_t)c3 * 16 + gl];
        addh8(acc, v0); addh8(acc, v1); addh8(acc, v2); addh8(acc, v3);
        i += 4;
    }
    int rem = cnt - i;
    if (rem > 0) {
        int c0 = csr[start + i];
        int c1 = csr[start + min(i + 1, cnt - 1)];
        int c2 = csr[start + min(i + 2, cnt - 1)];
        float4 v0 = base[(size_t)c0 * 16 + gl];
        float4 v1 = base[(size_t)c1 * 16 + gl];
        float4 v2 = base[(size_t)c2 * 16 + gl];
        addh8(acc, v0);
        if (rem > 1) addh8(acc, v1);
        if (rem > 2) addh8(acc, v2);
    }
}

// ---------------- fused: gather round-1 into LDS tile, then linear2 -> z2 ----------------
__global__ __launch_bounds__(512) void gather_linear_kernel(const __half* __restrict__ z1,
                                                            const int* __restrict__ offsets,
                                                            const int* __restrict__ deg,
                                                            const int* __restrict__ csr,
                                                            const float* __restrict__ rdeg,
                                                            const float* __restrict__ bias,
                                                            const __half* __restrict__ WB2,
                                                            __half* __restrict__ z2, int n) {
    __shared__ __half Hs[32][136];
    int t    = threadIdx.x;
    int wv   = t >> 6;
    int lane = t & 63;
    int g    = lane >> 4;
    int gl   = lane & 15;
    int lrow = wv * 4 + g;
    int node = blockIdx.x * 32 + lrow;

    if (node < n) {
        float acc[8] = {0.f, 0.f, 0.f, 0.f, 0.f, 0.f, 0.f, 0.f};
        gather_core((const float4*)z1, offsets[node], deg[node], gl, csr, acc);
        float rd = rdeg[node];
        float4 b0 = ((const float4*)bias)[gl * 2];
        float4 b1 = ((const float4*)bias)[gl * 2 + 1];
        __half2 hp[4];
        hp[0] = __float22half2_rn(make_float2(fmaxf(acc[0] * rd + b0.x, 0.f),
                                              fmaxf(acc[1] * rd + b0.y, 0.f)));
        hp[1] = __float22half2_rn(make_float2(fmaxf(acc[2] * rd + b0.z, 0.f),
                                              fmaxf(acc[3] * rd + b0.w, 0.f)));
        hp[2] = __float22half2_rn(make_float2(fmaxf(acc[4] * rd + b1.x, 0.f),
                                              fmaxf(acc[5] * rd + b1.y, 0.f)));
        hp[3] = __float22half2_rn(make_float2(fmaxf(acc[6] * rd + b1.z, 0.f),
                                              fmaxf(acc[7] * rd + b1.w, 0.f)));
        *(float4*)&Hs[lrow][gl * 8] = *(const float4*)hp;
    }
    __syncthreads();

    int r0 = (wv >> 2) * 16;
    int arow = r0 + (lane & 15);
    h8 a[4];
#pragma unroll
    for (int kk = 0; kk < 4; ++kk)
        a[kk] = *(const h8*)&Hs[arow][kk * 32 + (lane >> 4) * 8];

    int srow = blockIdx.x * 32 + r0 + (lane >> 4) * 4;
#pragma unroll
    for (int cc = 0; cc < 2; ++cc) {
        int c = (wv & 3) * 2 + cc;
        f4 acc = {0.f, 0.f, 0.f, 0.f};
#pragma unroll
        for (int kk = 0; kk < 4; ++kk) {
            h8 b = *(const h8*)&WB2[(((c * 4 + kk) * 64) + lane) * 8];
            acc = __builtin_amdgcn_mfma_f32_16x16x32_f16(a[kk], b, acc, 0, 0, 0);
        }
        int col = c * 16 + (lane & 15);
#pragma unroll
        for (int r = 0; r < 4; ++r) {
            int ro = srow + r;
            if (ro < n) z2[(size_t)ro * D + col] = __float2half(acc[r]);
        }
    }
}

// ---------------- final gather: z2 -> out (f32) ----------------
__global__ __launch_bounds__(256) void gather_kernel(const __half* __restrict__ z,
                                                     const int* __restrict__ offsets,
                                                     const int* __restrict__ deg,
                                                     const int* __restrict__ csr,
                                                     const float* __restrict__ rdeg,
                                                     const float* __restrict__ bias,
                                                     float* __restrict__ out, int n) {
    int tid  = blockIdx.x * 256 + threadIdx.x;
    int wave = tid >> 6;
    int lane = threadIdx.x & 63;
    int g    = lane >> 4;
    int gl   = lane & 15;
    int node = wave * 4 + g;
    if (node >= n) return;

    float acc[8] = {0.f, 0.f, 0.f, 0.f, 0.f, 0.f, 0.f, 0.f};
    gather_core((const float4*)z, offsets[node], deg[node], gl, csr, acc);

    float rd = rdeg[node];
    float4 b0 = ((const float4*)bias)[gl * 2];
    float4 b1 = ((const float4*)bias)[gl * 2 + 1];
    float4* o4 = (float4*)out;
    o4[(size_t)node * 32 + gl * 2] =
        make_float4(fmaxf(acc[0] * rd + b0.x, 0.f), fmaxf(acc[1] * rd + b0.y, 0.f),
                    fmaxf(acc[2] * rd + b0.z, 0.f), fmaxf(acc[3] * rd + b0.w, 0.f));
    o4[(size_t)node * 32 + gl * 2 + 1] =
        make_float4(fmaxf(acc[4] * rd + b1.x, 0.f), fmaxf(acc[5] * rd + b1.y, 0.f),
                    fmaxf(acc[6] * rd + b1.z, 0.f), fmaxf(acc[7] * rd + b1.w, 0.f));
}

extern "C" void kernel_launch(void* const* d_in, const int* in_sizes, int n_in,
                              void* d_out, int out_size, void* d_ws, size_t ws_size,
                              hipStream_t stream) {
    const float* x  = (const float*)d_in[0];
    const int*   ei = (const int*)d_in[1];
    const float* W1 = (const float*)d_in[2];
    const float* b1 = (const float*)d_in[3];
    const float* W2 = (const float*)d_in[4];
    const float* b2 = (const float*)d_in[5];
    float* out = (float*)d_out;

    int N = in_sizes[0] / D;   // 50000
    int E = in_sizes[1] / 2;   // 600000
    int NB = (N + 255) / 256;  // 196

    // workspace carve (16B-aligned: N, E multiples of 4)
    int* hist8   = (int*)d_ws;               // [NC][N]
    int* cursor8 = hist8 + NC * N;           // [NC][N]
    int* offsets = cursor8 + NC * N;
    int* deg     = offsets + N;
    int* csr     = deg + N;
    float* rdeg  = (float*)(csr + E);
    int* bsum    = (int*)(rdeg + N);
    __half* WB1  = (__half*)(bsum + ((NB + 3) & ~3));
    __half* WB2  = WB1 + D * D;
    __half* zz   = WB2 + D * D;              // z1, fp16 [N][D]
    __half* zz2  = zz + (size_t)N * D;       // z2, fp16 [N][D]

    int NZ    = (NC * N + 255) / 256;              // hist8 zero blocks
    int nhist = (E + 255) / 256;                   // 2344
    int nblk  = (N + TILE_R - 1) / TILE_R;         // 782 (round-1 linear)
    int gfblk = (N + 31) / 32;                     // 1563 (fused gather+linear2)
    int gblk  = ((N + 3) / 4 * 64 + 255) / 256;    // final gather blocks

    prep_kernel<<<NZ + 2, 256, 0, stream>>>(hist8, NC * N, W1, WB1, W2, WB2);
    // fused: z1 = x @ W1^T (blocks 0..nblk-1) + privatized histogram (rest)
    hist_linear_kernel<<<nblk + nhist, 256, 0, stream>>>(ei, E, hist8, nblk, x, WB1, zz, N);
    partial_kernel<<<NB, 256, 0, stream>>>(hist8, bsum, N);
    finalize_kernel<<<NB, 256, 0, stream>>>(hist8, bsum, offsets, deg, cursor8, rdeg, N);
    fill_kernel<<<nhist, 256, 0, stream>>>(ei, E, cursor8, csr, N);
    // fused: h = relu(S z1 + b1) ; z2 = h @ W2^T
    gather_linear_kernel<<<gfblk, 512, 0, stream>>>(zz, offsets, deg, csr, rdeg, b1,
                                                    WB2, zz2, N);
    // final: out = relu(S z2 + b2)
    gather_kernel<<<gblk, 256, 0, stream>>>(zz2, offsets, deg, csr, rdeg, b2, out, N);
}

// Round 19
// 145.044 us; speedup vs baseline: 1.5497x; 1.0391x over previous
//
#include <hip/hip_runtime.h>
#include <hip/hip_fp16.h>

#define D 128
#define TILE_R 64
#define NC 8   // histogram/cursor privatization copies (r16 optimum; r18 showed 16 is net-negative)

typedef _Float16 h8 __attribute__((ext_vector_type(8)));
typedef float f4 __attribute__((ext_vector_type(4)));

// ---------------- prep: zero hist8 + build MFMA fragment-ready W buffers ----------------
__global__ __launch_bounds__(256) void prep_kernel(int* __restrict__ hist8, int n8,
                                                   const float* __restrict__ W1,
                                                   __half* __restrict__ WB1,
                                                   const float* __restrict__ W2,
                                                   __half* __restrict__ WB2) {
    if (blockIdx.x < 2) {
        const float* W = blockIdx.x ? W2 : W1;
        __half* WB     = blockIdx.x ? WB2 : WB1;
        for (int idx = threadIdx.x; idx < D * D; idx += 256) {
            int j  = idx & 7;
            int l  = (idx >> 3) & 63;
            int kk = (idx >> 9) & 3;
            int c  = idx >> 11;
            int k   = kk * 32 + (l >> 4) * 8 + j;
            int col = c * 16 + (l & 15);
            WB[idx] = __float2half(W[col * D + k]);
        }
        return;
    }
    int i = (blockIdx.x - 2) * 256 + threadIdx.x;
    if (i < n8) hist8[i] = 0;
}

// ---------------- fragment loaders ----------------
__device__ inline h8 load_frag(const __half* p) { return *(const h8*)p; }
__device__ inline h8 load_frag(const float* p) {
    float4 u = *(const float4*)p;
    float4 v = *(const float4*)(p + 4);
    h8 r;
    r[0] = (_Float16)u.x; r[1] = (_Float16)u.y; r[2] = (_Float16)u.z; r[3] = (_Float16)u.w;
    r[4] = (_Float16)v.x; r[5] = (_Float16)v.y; r[6] = (_Float16)v.z; r[7] = (_Float16)v.w;
    return r;
}

// ---------------- MFMA linear with LDS-coalesced stores ----------------
template <typename T>
__device__ inline void linear_coal(const T* __restrict__ src,
                                   const __half* __restrict__ WB,
                                   __half* __restrict__ z, int n, int blk) {
    __shared__ __half Zs[64][132];
    int l    = threadIdx.x & 63;
    int wv   = threadIdx.x >> 6;
    int row0 = blk * TILE_R + wv * 16;
    int arow = row0 + (l & 15);
    bool rowok = arow < n;

    h8 a[4];
#pragma unroll
    for (int kk = 0; kk < 4; ++kk) {
        if (rowok)
            a[kk] = load_frag(&src[(size_t)arow * D + kk * 32 + (l >> 4) * 8]);
        else
            a[kk] = (h8)(_Float16)0.0f;
    }

    int lr0 = wv * 16 + (l >> 4) * 4;
#pragma unroll
    for (int c = 0; c < 8; ++c) {
        f4 acc = {0.f, 0.f, 0.f, 0.f};
#pragma unroll
        for (int kk = 0; kk < 4; ++kk) {
            h8 b = *(const h8*)&WB[(((c * 4 + kk) * 64) + l) * 8];
            acc = __builtin_amdgcn_mfma_f32_16x16x32_f16(a[kk], b, acc, 0, 0, 0);
        }
        int col = c * 16 + (l & 15);
#pragma unroll
        for (int r = 0; r < 4; ++r) Zs[lr0 + r][col] = __float2half(acc[r]);
    }
    __syncthreads();

    int row = threadIdx.x >> 2;
    int cb  = (threadIdx.x & 3) * 32;
    int gro = blk * TILE_R + row;
    if (gro < n) {
        float2 p0 = *(const float2*)&Zs[row][cb];
        float2 p1 = *(const float2*)&Zs[row][cb + 4];
        float2 p2 = *(const float2*)&Zs[row][cb + 8];
        float2 p3 = *(const float2*)&Zs[row][cb + 12];
        float2 p4 = *(const float2*)&Zs[row][cb + 16];
        float2 p5 = *(const float2*)&Zs[row][cb + 20];
        float2 p6 = *(const float2*)&Zs[row][cb + 24];
        float2 p7 = *(const float2*)&Zs[row][cb + 28];
        __half* zp = &z[(size_t)gro * D + cb];
        *(float4*)(zp)      = make_float4(p0.x, p0.y, p1.x, p1.y);
        *(float4*)(zp + 8)  = make_float4(p2.x, p2.y, p3.x, p3.y);
        *(float4*)(zp + 16) = make_float4(p4.x, p4.y, p5.x, p5.y);
        *(float4*)(zp + 24) = make_float4(p6.x, p6.y, p7.x, p7.y);
    }
}

// ---------------- fused: round-1 linear (blocks 0..nlin-1) + histogram (rest) ----------------
__global__ __launch_bounds__(256) void hist_linear_kernel(const int* __restrict__ ei, int e,
                                                          int* __restrict__ hist8, int nlin,
                                                          const float* __restrict__ x,
                                                          const __half* __restrict__ WB,
                                                          __half* __restrict__ z, int n) {
    if (blockIdx.x >= nlin) {
        int chunk = blockIdx.x - nlin;
        int i = chunk * 256 + threadIdx.x;
        if (i < e) atomicAdd(&hist8[(chunk & (NC - 1)) * n + ei[i]], 1);
        return;
    }
    linear_coal<float>(x, WB, z, n, blockIdx.x);
}

// ---------------- per-block partial sums over node totals ----------------
__global__ __launch_bounds__(256) void partial_kernel(const int* __restrict__ hist8,
                                                      int* __restrict__ bsum, int n) {
    int i = blockIdx.x * 256 + threadIdx.x;
    int v = 0;
    if (i < n) {
#pragma unroll
        for (int c = 0; c < NC; ++c) v += hist8[c * n + i];
    }
#pragma unroll
    for (int off = 1; off < 64; off <<= 1) v += __shfl_xor(v, off);
    __shared__ int ws[4];
    int lane = threadIdx.x & 63, w = threadIdx.x >> 6;
    if (lane == 0) ws[w] = v;
    __syncthreads();
    if (threadIdx.x == 0) bsum[blockIdx.x] = ws[0] + ws[1] + ws[2] + ws[3];
}

// ---------------- finalize: offsets/deg/rdeg + per-copy sub-segment cursors ----------------
__global__ __launch_bounds__(256) void finalize_kernel(const int* __restrict__ hist8,
                                                       const int* __restrict__ bsum,
                                                       int* __restrict__ offsets,
                                                       int* __restrict__ deg,
                                                       int* __restrict__ cursor8,
                                                       float* __restrict__ rdeg, int n) {
    __shared__ int wt[4];
    int t = threadIdx.x, lane = t & 63, w = t >> 6;

    int p = 0;
    for (int k = t; k < blockIdx.x; k += 256) p += bsum[k];
#pragma unroll
    for (int off = 1; off < 64; off <<= 1) p += __shfl_xor(p, off);
    if (lane == 0) wt[w] = p;
    __syncthreads();
    int blockbase = wt[0] + wt[1] + wt[2] + wt[3];
    __syncthreads();

    int i = blockIdx.x * 256 + t;
    int cnt[NC];
    int tot = 0;
    if (i < n) {
#pragma unroll
        for (int c = 0; c < NC; ++c) { cnt[c] = hist8[c * n + i]; tot += cnt[c]; }
    } else {
#pragma unroll
        for (int c = 0; c < NC; ++c) cnt[c] = 0;
    }
    int iv = tot;
#pragma unroll
    for (int off = 1; off < 64; off <<= 1) {
        int n2 = __shfl_up(iv, off);
        if (lane >= off) iv += n2;
    }
    if (lane == 63) wt[w] = iv;
    __syncthreads();
    int add = blockbase;
    for (int k = 0; k < w; ++k) add += wt[k];
    int excl = iv - tot + add;
    if (i < n) {
        offsets[i] = excl;
        deg[i]     = tot;
        rdeg[i]    = 1.0f / fmaxf((float)tot, 1.0f);
        int run = excl;
#pragma unroll
        for (int c = 0; c < NC; ++c) { cursor8[c * n + i] = run; run += cnt[c]; }
    }
}

// ---------------- fill CSR via privatized cursors (copy = edge chunk & (NC-1)) ----------------
__global__ __launch_bounds__(256) void fill_kernel(const int* __restrict__ ei, int e,
                                                   int* __restrict__ cursor8,
                                                   int* __restrict__ csr, int n) {
    int i = blockIdx.x * 256 + threadIdx.x;
    if (i < e) {
        int r = ei[i];
        int c = ei[e + i];
        int pos = atomicAdd(&cursor8[(blockIdx.x & (NC - 1)) * n + r], 1);
        csr[pos] = c;
    }
}

// ---------------- gather core: accumulate node's neighbor rows of z (fp16) ----------------
// Full 8-batches, then ONE clamped-masked 8-batch tail (all loads issue immediately;
// masked lanes re-read the last neighbor's row -> L2 hit). Max 2 serial epochs for deg<=16.
__device__ inline void addh8(float* a, float4 v) {
    const __half2* h = (const __half2*)&v;
    float2 f0 = __half22float2(h[0]);
    float2 f1 = __half22float2(h[1]);
    float2 f2 = __half22float2(h[2]);
    float2 f3 = __half22float2(h[3]);
    a[0] += f0.x; a[1] += f0.y; a[2] += f1.x; a[3] += f1.y;
    a[4] += f2.x; a[5] += f2.y; a[6] += f3.x; a[7] += f3.y;
}

__device__ inline void gather_core(const float4* __restrict__ base, int start, int cnt,
                                   int gl, const int* __restrict__ csr, float* acc) {
    int i = 0;
    for (; i + 8 <= cnt; i += 8) {
        int c0 = csr[start + i];
        int c1 = csr[start + i + 1];
        int c2 = csr[start + i + 2];
        int c3 = csr[start + i + 3];
        int c4 = csr[start + i + 4];
        int c5 = csr[start + i + 5];
        int c6 = csr[start + i + 6];
        int c7 = csr[start + i + 7];
        float4 v0 = base[(size_t)c0 * 16 + gl];
        float4 v1 = base[(size_t)c1 * 16 + gl];
        float4 v2 = base[(size_t)c2 * 16 + gl];
        float4 v3 = base[(size_t)c3 * 16 + gl];
        float4 v4 = base[(size_t)c4 * 16 + gl];
        float4 v5 = base[(size_t)c5 * 16 + gl];
        float4 v6 = base[(size_t)c6 * 16 + gl];
        float4 v7 = base[(size_t)c7 * 16 + gl];
        addh8(acc, v0); addh8(acc, v1); addh8(acc, v2); addh8(acc, v3);
        addh8(acc, v4); addh8(acc, v5); addh8(acc, v6); addh8(acc, v7);
    }
    if (i < cnt) {
        int last = cnt - 1;
        int c0 = csr[start + i];
        int c1 = csr[start + min(i + 1, last)];
        int c2 = csr[start + min(i + 2, last)];
        int c3 = csr[start + min(i + 3, last)];
        int c4 = csr[start + min(i + 4, last)];
        int c5 = csr[start + min(i + 5, last)];
        int c6 = csr[start + min(i + 6, last)];
        int c7 = csr[start + min(i + 7, last)];
        float4 v0 = base[(size_t)c0 * 16 + gl];
        float4 v1 = base[(size_t)c1 * 16 + gl];
        float4 v2 = base[(size_t)c2 * 16 + gl];
        float4 v3 = base[(size_t)c3 * 16 + gl];
        float4 v4 = base[(size_t)c4 * 16 + gl];
        float4 v5 = base[(size_t)c5 * 16 + gl];
        float4 v6 = base[(size_t)c6 * 16 + gl];
        float4 v7 = base[(size_t)c7 * 16 + gl];
        int rem = cnt - i;
        addh8(acc, v0);
        if (rem > 1) addh8(acc, v1);
        if (rem > 2) addh8(acc, v2);
        if (rem > 3) addh8(acc, v3);
        if (rem > 4) addh8(acc, v4);
        if (rem > 5) addh8(acc, v5);
        if (rem > 6) addh8(acc, v6);
        if (rem > 7) addh8(acc, v7);
    }
}

// ---------------- fused: gather round-1 into LDS tile, then linear2 -> z2 ----------------
__global__ __launch_bounds__(512) void gather_linear_kernel(const __half* __restrict__ z1,
                                                            const int* __restrict__ offsets,
                                                            const int* __restrict__ deg,
                                                            const int* __restrict__ csr,
                                                            const float* __restrict__ rdeg,
                                                            const float* __restrict__ bias,
                                                            const __half* __restrict__ WB2,
                                                            __half* __restrict__ z2, int n) {
    __shared__ __half Hs[32][136];
    int t    = threadIdx.x;
    int wv   = t >> 6;
    int lane = t & 63;
    int g    = lane >> 4;
    int gl   = lane & 15;
    int lrow = wv * 4 + g;
    int node = blockIdx.x * 32 + lrow;

    if (node < n) {
        float acc[8] = {0.f, 0.f, 0.f, 0.f, 0.f, 0.f, 0.f, 0.f};
        gather_core((const float4*)z1, offsets[node], deg[node], gl, csr, acc);
        float rd = rdeg[node];
        float4 b0 = ((const float4*)bias)[gl * 2];
        float4 b1 = ((const float4*)bias)[gl * 2 + 1];
        __half2 hp[4];
        hp[0] = __float22half2_rn(make_float2(fmaxf(acc[0] * rd + b0.x, 0.f),
                                              fmaxf(acc[1] * rd + b0.y, 0.f)));
        hp[1] = __float22half2_rn(make_float2(fmaxf(acc[2] * rd + b0.z, 0.f),
                                              fmaxf(acc[3] * rd + b0.w, 0.f)));
        hp[2] = __float22half2_rn(make_float2(fmaxf(acc[4] * rd + b1.x, 0.f),
                                              fmaxf(acc[5] * rd + b1.y, 0.f)));
        hp[3] = __float22half2_rn(make_float2(fmaxf(acc[6] * rd + b1.z, 0.f),
                                              fmaxf(acc[7] * rd + b1.w, 0.f)));
        *(float4*)&Hs[lrow][gl * 8] = *(const float4*)hp;
    }
    __syncthreads();

    int r0 = (wv >> 2) * 16;
    int arow = r0 + (lane & 15);
    h8 a[4];
#pragma unroll
    for (int kk = 0; kk < 4; ++kk)
        a[kk] = *(const h8*)&Hs[arow][kk * 32 + (lane >> 4) * 8];

    int srow = blockIdx.x * 32 + r0 + (lane >> 4) * 4;
#pragma unroll
    for (int cc = 0; cc < 2; ++cc) {
        int c = (wv & 3) * 2 + cc;
        f4 acc = {0.f, 0.f, 0.f, 0.f};
#pragma unroll
        for (int kk = 0; kk < 4; ++kk) {
            h8 b = *(const h8*)&WB2[(((c * 4 + kk) * 64) + lane) * 8];
            acc = __builtin_amdgcn_mfma_f32_16x16x32_f16(a[kk], b, acc, 0, 0, 0);
        }
        int col = c * 16 + (lane & 15);
#pragma unroll
        for (int r = 0; r < 4; ++r) {
            int ro = srow + r;
            if (ro < n) z2[(size_t)ro * D + col] = __float2half(acc[r]);
        }
    }
}

// ---------------- final gather: z2 -> out (f32) ----------------
__global__ __launch_bounds__(256) void gather_kernel(const __half* __restrict__ z,
                                                     const int* __restrict__ offsets,
                                                     const int* __restrict__ deg,
                                                     const int* __restrict__ csr,
                                                     const float* __restrict__ rdeg,
                                                     const float* __restrict__ bias,
                                                     float* __restrict__ out, int n) {
    int tid  = blockIdx.x * 256 + threadIdx.x;
    int wave = tid >> 6;
    int lane = threadIdx.x & 63;
    int g    = lane >> 4;
    int gl   = lane & 15;
    int node = wave * 4 + g;
    if (node >= n) return;

    float acc[8] = {0.f, 0.f, 0.f, 0.f, 0.f, 0.f, 0.f, 0.f};
    gather_core((const float4*)z, offsets[node], deg[node], gl, csr, acc);

    float rd = rdeg[node];
    float4 b0 = ((const float4*)bias)[gl * 2];
    float4 b1 = ((const float4*)bias)[gl * 2 + 1];
    float4* o4 = (float4*)out;
    o4[(size_t)node * 32 + gl * 2] =
        make_float4(fmaxf(acc[0] * rd + b0.x, 0.f), fmaxf(acc[1] * rd + b0.y, 0.f),
                    fmaxf(acc[2] * rd + b0.z, 0.f), fmaxf(acc[3] * rd + b0.w, 0.f));
    o4[(size_t)node * 32 + gl * 2 + 1] =
        make_float4(fmaxf(acc[4] * rd + b1.x, 0.f), fmaxf(acc[5] * rd + b1.y, 0.f),
                    fmaxf(acc[6] * rd + b1.z, 0.f), fmaxf(acc[7] * rd + b1.w, 0.f));
}

extern "C" void kernel_launch(void* const* d_in, const int* in_sizes, int n_in,
                              void* d_out, int out_size, void* d_ws, size_t ws_size,
                              hipStream_t stream) {
    const float* x  = (const float*)d_in[0];
    const int*   ei = (const int*)d_in[1];
    const float* W1 = (const float*)d_in[2];
    const float* b1 = (const float*)d_in[3];
    const float* W2 = (const float*)d_in[4];
    const float* b2 = (const float*)d_in[5];
    float* out = (float*)d_out;

    int N = in_sizes[0] / D;   // 50000
    int E = in_sizes[1] / 2;   // 600000
    int NB = (N + 255) / 256;  // 196

    // workspace carve (16B-aligned: N, E multiples of 4)
    int* hist8   = (int*)d_ws;               // [NC][N]
    int* cursor8 = hist8 + NC * N;           // [NC][N]
    int* offsets = cursor8 + NC * N;
    int* deg     = offsets + N;
    int* csr     = deg + N;
    float* rdeg  = (float*)(csr + E);
    int* bsum    = (int*)(rdeg + N);
    __half* WB1  = (__half*)(bsum + ((NB + 3) & ~3));
    __half* WB2  = WB1 + D * D;
    __half* zz   = WB2 + D * D;              // z1, fp16 [N][D]
    __half* zz2  = zz + (size_t)N * D;       // z2, fp16 [N][D]

    int NZ    = (NC * N + 255) / 256;              // hist8 zero blocks
    int nhist = (E + 255) / 256;                   // 2344
    int nblk  = (N + TILE_R - 1) / TILE_R;         // 782 (round-1 linear)
    int gfblk = (N + 31) / 32;                     // 1563 (fused gather+linear2)
    int gblk  = ((N + 3) / 4 * 64 + 255) / 256;    // final gather blocks

    prep_kernel<<<NZ + 2, 256, 0, stream>>>(hist8, NC * N, W1, WB1, W2, WB2);
    // fused: z1 = x @ W1^T (blocks 0..nblk-1) + privatized histogram (rest)
    hist_linear_kernel<<<nblk + nhist, 256, 0, stream>>>(ei, E, hist8, nblk, x, WB1, zz, N);
    partial_kernel<<<NB, 256, 0, stream>>>(hist8, bsum, N);
    finalize_kernel<<<NB, 256, 0, stream>>>(hist8, bsum, offsets, deg, cursor8, rdeg, N);
    fill_kernel<<<nhist, 256, 0, stream>>>(ei, E, cursor8, csr, N);
    // fused: h = relu(S z1 + b1) ; z2 = h @ W2^T
    gather_linear_kernel<<<gfblk, 512, 0, stream>>>(zz, offsets, deg, csr, rdeg, b1,
                                                    WB2, zz2, N);
    // final: out = relu(S z2 + b2)
    gather_kernel<<<gblk, 256, 0, stream>>>(zz2, offsets, deg, csr, rdeg, b2, out, N);
}

// Round 20
// 143.281 us; speedup vs baseline: 1.5688x; 1.0123x over previous
//
#include <hip/hip_runtime.h>
#include <hip/hip_fp16.h>

#define D 128
#define TILE_R 64
#define NC 8   // histogram/cursor privatization copies (r16/r18/r19: measured optimum)

typedef _Float16 h8 __attribute__((ext_vector_type(8)));
typedef float f4 __attribute__((ext_vector_type(4)));

// ---------------- prep: zero hist8 + build MFMA fragment-ready W buffers ----------------
__global__ __launch_bounds__(256) void prep_kernel(int* __restrict__ hist8, int n8,
                                                   const float* __restrict__ W1,
                                                   __half* __restrict__ WB1,
                                                   const float* __restrict__ W2,
                                                   __half* __restrict__ WB2) {
    if (blockIdx.x < 2) {
        const float* W = blockIdx.x ? W2 : W1;
        __half* WB     = blockIdx.x ? WB2 : WB1;
        for (int idx = threadIdx.x; idx < D * D; idx += 256) {
            int j  = idx & 7;
            int l  = (idx >> 3) & 63;
            int kk = (idx >> 9) & 3;
            int c  = idx >> 11;
            int k   = kk * 32 + (l >> 4) * 8 + j;
            int col = c * 16 + (l & 15);
            WB[idx] = __float2half(W[col * D + k]);
        }
        return;
    }
    int i = (blockIdx.x - 2) * 256 + threadIdx.x;
    if (i < n8) hist8[i] = 0;
}

// ---------------- fragment loaders ----------------
__device__ inline h8 load_frag(const __half* p) { return *(const h8*)p; }
__device__ inline h8 load_frag(const float* p) {
    float4 u = *(const float4*)p;
    float4 v = *(const float4*)(p + 4);
    h8 r;
    r[0] = (_Float16)u.x; r[1] = (_Float16)u.y; r[2] = (_Float16)u.z; r[3] = (_Float16)u.w;
    r[4] = (_Float16)v.x; r[5] = (_Float16)v.y; r[6] = (_Float16)v.z; r[7] = (_Float16)v.w;
    return r;
}

// ---------------- MFMA linear with LDS-coalesced stores ----------------
template <typename T>
__device__ inline void linear_coal(const T* __restrict__ src,
                                   const __half* __restrict__ WB,
                                   __half* __restrict__ z, int n, int blk) {
    __shared__ __half Zs[64][132];
    int l    = threadIdx.x & 63;
    int wv   = threadIdx.x >> 6;
    int row0 = blk * TILE_R + wv * 16;
    int arow = row0 + (l & 15);
    bool rowok = arow < n;

    h8 a[4];
#pragma unroll
    for (int kk = 0; kk < 4; ++kk) {
        if (rowok)
            a[kk] = load_frag(&src[(size_t)arow * D + kk * 32 + (l >> 4) * 8]);
        else
            a[kk] = (h8)(_Float16)0.0f;
    }

    int lr0 = wv * 16 + (l >> 4) * 4;
#pragma unroll
    for (int c = 0; c < 8; ++c) {
        f4 acc = {0.f, 0.f, 0.f, 0.f};
#pragma unroll
        for (int kk = 0; kk < 4; ++kk) {
            h8 b = *(const h8*)&WB[(((c * 4 + kk) * 64) + l) * 8];
            acc = __builtin_amdgcn_mfma_f32_16x16x32_f16(a[kk], b, acc, 0, 0, 0);
        }
        int col = c * 16 + (l & 15);
#pragma unroll
        for (int r = 0; r < 4; ++r) Zs[lr0 + r][col] = __float2half(acc[r]);
    }
    __syncthreads();

    int row = threadIdx.x >> 2;
    int cb  = (threadIdx.x & 3) * 32;
    int gro = blk * TILE_R + row;
    if (gro < n) {
        float2 p0 = *(const float2*)&Zs[row][cb];
        float2 p1 = *(const float2*)&Zs[row][cb + 4];
        float2 p2 = *(const float2*)&Zs[row][cb + 8];
        float2 p3 = *(const float2*)&Zs[row][cb + 12];
        float2 p4 = *(const float2*)&Zs[row][cb + 16];
        float2 p5 = *(const float2*)&Zs[row][cb + 20];
        float2 p6 = *(const float2*)&Zs[row][cb + 24];
        float2 p7 = *(const float2*)&Zs[row][cb + 28];
        __half* zp = &z[(size_t)gro * D + cb];
        *(float4*)(zp)      = make_float4(p0.x, p0.y, p1.x, p1.y);
        *(float4*)(zp + 8)  = make_float4(p2.x, p2.y, p3.x, p3.y);
        *(float4*)(zp + 16) = make_float4(p4.x, p4.y, p5.x, p5.y);
        *(float4*)(zp + 24) = make_float4(p6.x, p6.y, p7.x, p7.y);
    }
}

// ---------------- fused: round-1 linear (blocks 0..nlin-1) + histogram (rest) ----------------
__global__ __launch_bounds__(256) void hist_linear_kernel(const int* __restrict__ ei, int e,
                                                          int* __restrict__ hist8, int nlin,
                                                          const float* __restrict__ x,
                                                          const __half* __restrict__ WB,
                                                          __half* __restrict__ z, int n) {
    if (blockIdx.x >= nlin) {
        int chunk = blockIdx.x - nlin;
        int i = chunk * 256 + threadIdx.x;
        if (i < e) atomicAdd(&hist8[(chunk & (NC - 1)) * n + ei[i]], 1);
        return;
    }
    linear_coal<float>(x, WB, z, n, blockIdx.x);
}

// ---------------- per-block partial sums over node totals ----------------
__global__ __launch_bounds__(256) void partial_kernel(const int* __restrict__ hist8,
                                                      int* __restrict__ bsum, int n) {
    int i = blockIdx.x * 256 + threadIdx.x;
    int v = 0;
    if (i < n) {
#pragma unroll
        for (int c = 0; c < NC; ++c) v += hist8[c * n + i];
    }
#pragma unroll
    for (int off = 1; off < 64; off <<= 1) v += __shfl_xor(v, off);
    __shared__ int ws[4];
    int lane = threadIdx.x & 63, w = threadIdx.x >> 6;
    if (lane == 0) ws[w] = v;
    __syncthreads();
    if (threadIdx.x == 0) bsum[blockIdx.x] = ws[0] + ws[1] + ws[2] + ws[3];
}

// ---------------- finalize: offsets/deg/rdeg + per-copy sub-segment cursors ----------------
__global__ __launch_bounds__(256) void finalize_kernel(const int* __restrict__ hist8,
                                                       const int* __restrict__ bsum,
                                                       int* __restrict__ offsets,
                                                       int* __restrict__ deg,
                                                       int* __restrict__ cursor8,
                                                       float* __restrict__ rdeg, int n) {
    __shared__ int wt[4];
    int t = threadIdx.x, lane = t & 63, w = t >> 6;

    int p = 0;
    for (int k = t; k < blockIdx.x; k += 256) p += bsum[k];
#pragma unroll
    for (int off = 1; off < 64; off <<= 1) p += __shfl_xor(p, off);
    if (lane == 0) wt[w] = p;
    __syncthreads();
    int blockbase = wt[0] + wt[1] + wt[2] + wt[3];
    __syncthreads();

    int i = blockIdx.x * 256 + t;
    int cnt[NC];
    int tot = 0;
    if (i < n) {
#pragma unroll
        for (int c = 0; c < NC; ++c) { cnt[c] = hist8[c * n + i]; tot += cnt[c]; }
    } else {
#pragma unroll
        for (int c = 0; c < NC; ++c) cnt[c] = 0;
    }
    int iv = tot;
#pragma unroll
    for (int off = 1; off < 64; off <<= 1) {
        int n2 = __shfl_up(iv, off);
        if (lane >= off) iv += n2;
    }
    if (lane == 63) wt[w] = iv;
    __syncthreads();
    int add = blockbase;
    for (int k = 0; k < w; ++k) add += wt[k];
    int excl = iv - tot + add;
    if (i < n) {
        offsets[i] = excl;
        deg[i]     = tot;
        rdeg[i]    = 1.0f / fmaxf((float)tot, 1.0f);
        int run = excl;
#pragma unroll
        for (int c = 0; c < NC; ++c) { cursor8[c * n + i] = run; run += cnt[c]; }
    }
}

// ---------------- fill CSR via privatized cursors (copy = edge chunk & (NC-1)) ----------------
__global__ __launch_bounds__(256) void fill_kernel(const int* __restrict__ ei, int e,
                                                   int* __restrict__ cursor8,
                                                   int* __restrict__ csr, int n) {
    int i = blockIdx.x * 256 + threadIdx.x;
    if (i < e) {
        int r = ei[i];
        int c = ei[e + i];
        int pos = atomicAdd(&cursor8[(blockIdx.x & (NC - 1)) * n + r], 1);
        csr[pos] = c;
    }
}

// ---------------- gather cores ----------------
__device__ inline void addh8(float* a, float4 v) {
    const __half2* h = (const __half2*)&v;
    float2 f0 = __half22float2(h[0]);
    float2 f1 = __half22float2(h[1]);
    float2 f2 = __half22float2(h[2]);
    float2 f3 = __half22float2(h[3]);
    a[0] += f0.x; a[1] += f0.y; a[2] += f1.x; a[3] += f1.y;
    a[4] += f2.x; a[5] += f2.y; a[6] += f3.x; a[7] += f3.y;
}

// 8-deep (used by 512-thr gather_linear: VGPR headroom matters there — r13 occupancy lesson)
__device__ inline void gather_core(const float4* __restrict__ base, int start, int cnt,
                                   int gl, const int* __restrict__ csr, float* acc) {
    int i = 0;
    for (; i + 8 <= cnt; i += 8) {
        int c0 = csr[start + i];
        int c1 = csr[start + i + 1];
        int c2 = csr[start + i + 2];
        int c3 = csr[start + i + 3];
        int c4 = csr[start + i + 4];
        int c5 = csr[start + i + 5];
        int c6 = csr[start + i + 6];
        int c7 = csr[start + i + 7];
        float4 v0 = base[(size_t)c0 * 16 + gl];
        float4 v1 = base[(size_t)c1 * 16 + gl];
        float4 v2 = base[(size_t)c2 * 16 + gl];
        float4 v3 = base[(size_t)c3 * 16 + gl];
        float4 v4 = base[(size_t)c4 * 16 + gl];
        float4 v5 = base[(size_t)c5 * 16 + gl];
        float4 v6 = base[(size_t)c6 * 16 + gl];
        float4 v7 = base[(size_t)c7 * 16 + gl];
        addh8(acc, v0); addh8(acc, v1); addh8(acc, v2); addh8(acc, v3);
        addh8(acc, v4); addh8(acc, v5); addh8(acc, v6); addh8(acc, v7);
    }
    if (i < cnt) {
        int last = cnt - 1;
        int c0 = csr[start + i];
        int c1 = csr[start + min(i + 1, last)];
        int c2 = csr[start + min(i + 2, last)];
        int c3 = csr[start + min(i + 3, last)];
        int c4 = csr[start + min(i + 4, last)];
        int c5 = csr[start + min(i + 5, last)];
        int c6 = csr[start + min(i + 6, last)];
        int c7 = csr[start + min(i + 7, last)];
        float4 v0 = base[(size_t)c0 * 16 + gl];
        float4 v1 = base[(size_t)c1 * 16 + gl];
        float4 v2 = base[(size_t)c2 * 16 + gl];
        float4 v3 = base[(size_t)c3 * 16 + gl];
        float4 v4 = base[(size_t)c4 * 16 + gl];
        float4 v5 = base[(size_t)c5 * 16 + gl];
        float4 v6 = base[(size_t)c6 * 16 + gl];
        float4 v7 = base[(size_t)c7 * 16 + gl];
        int rem = cnt - i;
        addh8(acc, v0);
        if (rem > 1) addh8(acc, v1);
        if (rem > 2) addh8(acc, v2);
        if (rem > 3) addh8(acc, v3);
        if (rem > 4) addh8(acc, v4);
        if (rem > 5) addh8(acc, v5);
        if (rem > 6) addh8(acc, v6);
        if (rem > 7) addh8(acc, v7);
    }
}

// 16-deep clamped (final gather only, 256-thr): deg<=16 (~82% of nodes) = ONE row-load epoch.
__device__ inline void gather_core16(const float4* __restrict__ base, int start, int cnt,
                                     int gl, const int* __restrict__ csr, float* acc) {
    int i = 0;
    for (; i + 16 <= cnt; i += 16) {
        int c[16];
#pragma unroll
        for (int k = 0; k < 16; ++k) c[k] = csr[start + i + k];
        float4 v[16];
#pragma unroll
        for (int k = 0; k < 16; ++k) v[k] = base[(size_t)c[k] * 16 + gl];
#pragma unroll
        for (int k = 0; k < 16; ++k) addh8(acc, v[k]);
    }
    if (i < cnt) {
        int last = cnt - 1;
        int c[16];
#pragma unroll
        for (int k = 0; k < 16; ++k) c[k] = csr[start + min(i + k, last)];
        float4 v[16];
#pragma unroll
        for (int k = 0; k < 16; ++k) v[k] = base[(size_t)c[k] * 16 + gl];
        int rem = cnt - i;
        addh8(acc, v[0]);
#pragma unroll
        for (int k = 1; k < 16; ++k)
            if (rem > k) addh8(acc, v[k]);
    }
}

// ---------------- fused: gather round-1 into LDS tile, then linear2 -> z2 ----------------
__global__ __launch_bounds__(512) void gather_linear_kernel(const __half* __restrict__ z1,
                                                            const int* __restrict__ offsets,
                                                            const int* __restrict__ deg,
                                                            const int* __restrict__ csr,
                                                            const float* __restrict__ rdeg,
                                                            const float* __restrict__ bias,
                                                            const __half* __restrict__ WB2,
                                                            __half* __restrict__ z2, int n) {
    __shared__ __half Hs[32][136];
    int t    = threadIdx.x;
    int wv   = t >> 6;
    int lane = t & 63;
    int g    = lane >> 4;
    int gl   = lane & 15;
    int lrow = wv * 4 + g;
    int node = blockIdx.x * 32 + lrow;

    if (node < n) {
        float acc[8] = {0.f, 0.f, 0.f, 0.f, 0.f, 0.f, 0.f, 0.f};
        gather_core((const float4*)z1, offsets[node], deg[node], gl, csr, acc);
        float rd = rdeg[node];
        float4 b0 = ((const float4*)bias)[gl * 2];
        float4 b1 = ((const float4*)bias)[gl * 2 + 1];
        __half2 hp[4];
        hp[0] = __float22half2_rn(make_float2(fmaxf(acc[0] * rd + b0.x, 0.f),
                                              fmaxf(acc[1] * rd + b0.y, 0.f)));
        hp[1] = __float22half2_rn(make_float2(fmaxf(acc[2] * rd + b0.z, 0.f),
                                              fmaxf(acc[3] * rd + b0.w, 0.f)));
        hp[2] = __float22half2_rn(make_float2(fmaxf(acc[4] * rd + b1.x, 0.f),
                                              fmaxf(acc[5] * rd + b1.y, 0.f)));
        hp[3] = __float22half2_rn(make_float2(fmaxf(acc[6] * rd + b1.z, 0.f),
                                              fmaxf(acc[7] * rd + b1.w, 0.f)));
        *(float4*)&Hs[lrow][gl * 8] = *(const float4*)hp;
    }
    __syncthreads();

    int r0 = (wv >> 2) * 16;
    int arow = r0 + (lane & 15);
    h8 a[4];
#pragma unroll
    for (int kk = 0; kk < 4; ++kk)
        a[kk] = *(const h8*)&Hs[arow][kk * 32 + (lane >> 4) * 8];

    int srow = blockIdx.x * 32 + r0 + (lane >> 4) * 4;
#pragma unroll
    for (int cc = 0; cc < 2; ++cc) {
        int c = (wv & 3) * 2 + cc;
        f4 acc = {0.f, 0.f, 0.f, 0.f};
#pragma unroll
        for (int kk = 0; kk < 4; ++kk) {
            h8 b = *(const h8*)&WB2[(((c * 4 + kk) * 64) + lane) * 8];
            acc = __builtin_amdgcn_mfma_f32_16x16x32_f16(a[kk], b, acc, 0, 0, 0);
        }
        int col = c * 16 + (lane & 15);
#pragma unroll
        for (int r = 0; r < 4; ++r) {
            int ro = srow + r;
            if (ro < n) z2[(size_t)ro * D + col] = __float2half(acc[r]);
        }
    }
}

// ---------------- final gather: z2 -> out (f32), 16-deep window ----------------
__global__ __launch_bounds__(256) void gather_kernel(const __half* __restrict__ z,
                                                     const int* __restrict__ offsets,
                                                     const int* __restrict__ deg,
                                                     const int* __restrict__ csr,
                                                     const float* __restrict__ rdeg,
                                                     const float* __restrict__ bias,
                                                     float* __restrict__ out, int n) {
    int tid  = blockIdx.x * 256 + threadIdx.x;
    int wave = tid >> 6;
    int lane = threadIdx.x & 63;
    int g    = lane >> 4;
    int gl   = lane & 15;
    int node = wave * 4 + g;
    if (node >= n) return;

    float acc[8] = {0.f, 0.f, 0.f, 0.f, 0.f, 0.f, 0.f, 0.f};
    gather_core16((const float4*)z, offsets[node], deg[node], gl, csr, acc);

    float rd = rdeg[node];
    float4 b0 = ((const float4*)bias)[gl * 2];
    float4 b1 = ((const float4*)bias)[gl * 2 + 1];
    float4* o4 = (float4*)out;
    o4[(size_t)node * 32 + gl * 2] =
        make_float4(fmaxf(acc[0] * rd + b0.x, 0.f), fmaxf(acc[1] * rd + b0.y, 0.f),
                    fmaxf(acc[2] * rd + b0.z, 0.f), fmaxf(acc[3] * rd + b0.w, 0.f));
    o4[(size_t)node * 32 + gl * 2 + 1] =
        make_float4(fmaxf(acc[4] * rd + b1.x, 0.f), fmaxf(acc[5] * rd + b1.y, 0.f),
                    fmaxf(acc[6] * rd + b1.z, 0.f), fmaxf(acc[7] * rd + b1.w, 0.f));
}

extern "C" void kernel_launch(void* const* d_in, const int* in_sizes, int n_in,
                              void* d_out, int out_size, void* d_ws, size_t ws_size,
                              hipStream_t stream) {
    const float* x  = (const float*)d_in[0];
    const int*   ei = (const int*)d_in[1];
    const float* W1 = (const float*)d_in[2];
    const float* b1 = (const float*)d_in[3];
    const float* W2 = (const float*)d_in[4];
    const float* b2 = (const float*)d_in[5];
    float* out = (float*)d_out;

    int N = in_sizes[0] / D;   // 50000
    int E = in_sizes[1] / 2;   // 600000
    int NB = (N + 255) / 256;  // 196

    // workspace carve (16B-aligned: N, E multiples of 4)
    int* hist8   = (int*)d_ws;               // [NC][N]
    int* cursor8 = hist8 + NC * N;           // [NC][N]
    int* offsets = cursor8 + NC * N;
    int* deg     = offsets + N;
    int* csr     = deg + N;
    float* rdeg  = (float*)(csr + E);
    int* bsum    = (int*)(rdeg + N);
    __half* WB1  = (__half*)(bsum + ((NB + 3) & ~3));
    __half* WB2  = WB1 + D * D;
    __half* zz   = WB2 + D * D;              // z1, fp16 [N][D]
    __half* zz2  = zz + (size_t)N * D;       // z2, fp16 [N][D]

    int NZ    = (NC * N + 255) / 256;              // hist8 zero blocks
    int nhist = (E + 255) / 256;                   // 2344
    int nblk  = (N + TILE_R - 1) / TILE_R;         // 782 (round-1 linear)
    int gfblk = (N + 31) / 32;                     // 1563 (fused gather+linear2)
    int gblk  = ((N + 3) / 4 * 64 + 255) / 256;    // final gather blocks

    prep_kernel<<<NZ + 2, 256, 0, stream>>>(hist8, NC * N, W1, WB1, W2, WB2);
    // fused: z1 = x @ W1^T (blocks 0..nblk-1) + privatized histogram (rest)
    hist_linear_kernel<<<nblk + nhist, 256, 0, stream>>>(ei, E, hist8, nblk, x, WB1, zz, N);
    partial_kernel<<<NB, 256, 0, stream>>>(hist8, bsum, N);
    finalize_kernel<<<NB, 256, 0, stream>>>(hist8, bsum, offsets, deg, cursor8, rdeg, N);
    fill_kernel<<<nhist, 256, 0, stream>>>(ei, E, cursor8, csr, N);
    // fused: h = relu(S z1 + b1) ; z2 = h @ W2^T
    gather_linear_kernel<<<gfblk, 512, 0, stream>>>(zz, offsets, deg, csr, rdeg, b1,
                                                    WB2, zz2, N);
    // final: out = relu(S z2 + b2), 16-deep gather window
    gather_kernel<<<gblk, 256, 0, stream>>>(zz2, offsets, deg, csr, rdeg, b2, out, N);
}